// Round 1
// baseline (463.594 us; speedup 1.0000x reference)
//
#include <hip/hip_runtime.h>
#include <math.h>

#define DD    128      // embedding dim
#define BM    64       // rows per block
#define BN    64       // cols per tile
#define KC    64       // K chunk
#define PADW  68       // LDS floats per row (KC + 4 pad)
#define NPART 4        // j-range partitions (grid = 128*4 = 512 blocks)

__global__ __launch_bounds__(256)
void sqnorm_k(const float* __restrict__ emb, float* __restrict__ sq, int n) {
    int i = blockIdx.x * blockDim.x + threadIdx.x;
    if (i >= n) return;
    const float4* r = reinterpret_cast<const float4*>(emb) + (size_t)i * (DD / 4);
    float s = 0.f;
#pragma unroll
    for (int k = 0; k < DD / 4; ++k) {
        float4 v = r[k];
        s = fmaf(v.x, v.x, s);
        s = fmaf(v.y, v.y, s);
        s = fmaf(v.z, v.z, s);
        s = fmaf(v.w, v.w, s);
    }
    sq[i] = s;
}

__global__ __launch_bounds__(256, 4)
void hardest_k(const float* __restrict__ emb, const int* __restrict__ lab,
               const float* __restrict__ sq, float* __restrict__ hp_part,
               float* __restrict__ hn_part, int n) {
    __shared__ float As[BM][PADW];
    __shared__ float Bs[BN][PADW];
    __shared__ float sqB[BN];
    __shared__ int   lbB[BN];

    const int tid = threadIdx.x;
    const int tx  = tid & 15;          // 0..15 -> 4 cols each
    const int ty  = tid >> 4;          // 0..15 -> 4 rows each
    const int ib   = (int)blockIdx.x >> 2;   // row block 0..127
    const int part = (int)blockIdx.x & 3;    // j partition 0..3

    const int i0     = ib * BM;
    const int jcount = n / NPART;
    const int jbeg   = part * jcount;
    const int jend   = jbeg + jcount;

    int   myLab[4];
    float mySq[4], hpv[4], hnv[4];
#pragma unroll
    for (int r = 0; r < 4; ++r) {
        int i = i0 + ty * 4 + r;
        myLab[r] = lab[i];
        mySq[r]  = sq[i];
        hpv[r] = -INFINITY;
        hnv[r] =  INFINITY;
    }

    for (int j0 = jbeg; j0 < jend; j0 += BN) {
        float acc[4][4];
#pragma unroll
        for (int r = 0; r < 4; ++r)
#pragma unroll
            for (int c = 0; c < 4; ++c) acc[r][c] = 0.f;

#pragma unroll
        for (int kc = 0; kc < DD; kc += KC) {
            __syncthreads();
            if (kc == 0 && tid < BN) {
                sqB[tid] = sq[j0 + tid];
                lbB[tid] = lab[j0 + tid];
            }
            // stage A and B chunks (64 rows x 64 floats each), k-rotated per row
#pragma unroll
            for (int t = 0; t < 4; ++t) {
                int f   = t * 256 + tid;
                int row = f >> 4;      // 0..63
                int kq  = f & 15;      // float4 index within chunk
                int pC  = ((kq + (row >> 2)) & 15) * 4;   // rotated physical col
                float4 va = *reinterpret_cast<const float4*>(
                    &emb[(size_t)(i0 + row) * DD + kc + kq * 4]);
                float4 vb = *reinterpret_cast<const float4*>(
                    &emb[(size_t)(j0 + row) * DD + kc + kq * 4]);
                *reinterpret_cast<float4*>(&As[row][pC]) = va;
                *reinterpret_cast<float4*>(&Bs[row][pC]) = vb;
            }
            __syncthreads();
#pragma unroll
            for (int s = 0; s < 16; ++s) {
                int pa = ((s + ty) & 15) * 4;   // undo rotation (row>>2 == ty for A rows)
                int pb = ((s + tx) & 15) * 4;   // row>>2 == tx for B rows
                float4 a[4], b[4];
#pragma unroll
                for (int r = 0; r < 4; ++r)
                    a[r] = *reinterpret_cast<const float4*>(&As[ty * 4 + r][pa]);
#pragma unroll
                for (int c = 0; c < 4; ++c)
                    b[c] = *reinterpret_cast<const float4*>(&Bs[tx * 4 + c][pb]);
#pragma unroll
                for (int r = 0; r < 4; ++r)
#pragma unroll
                    for (int c = 0; c < 4; ++c) {
                        acc[r][c] = fmaf(a[r].x, b[c].x, acc[r][c]);
                        acc[r][c] = fmaf(a[r].y, b[c].y, acc[r][c]);
                        acc[r][c] = fmaf(a[r].z, b[c].z, acc[r][c]);
                        acc[r][c] = fmaf(a[r].w, b[c].w, acc[r][c]);
                    }
            }
        }
        // fused epilogue: distance + masked hardest-pos/neg update
#pragma unroll
        for (int r = 0; r < 4; ++r) {
            int i = i0 + ty * 4 + r;
#pragma unroll
            for (int c = 0; c < 4; ++c) {
                int j = j0 + tx * 4 + c;
                float d2   = mySq[r] + sqB[tx * 4 + c] - 2.f * acc[r][c];
                float dist = d2 > 0.f ? sqrtf(d2) : 0.f;
                bool  same = (myLab[r] == lbB[tx * 4 + c]);
                float dpos = (same && (i != j)) ? dist : -INFINITY;
                float dneg = same ? INFINITY : dist;
                hpv[r] = fmaxf(hpv[r], dpos);
                hnv[r] = fminf(hnv[r], dneg);
            }
        }
    }
    // reduce across the 16 tx-lanes sharing each row group
#pragma unroll
    for (int off = 1; off < 16; off <<= 1) {
#pragma unroll
        for (int r = 0; r < 4; ++r) {
            hpv[r] = fmaxf(hpv[r], __shfl_xor(hpv[r], off, 64));
            hnv[r] = fminf(hnv[r], __shfl_xor(hnv[r], off, 64));
        }
    }
    if (tx == 0) {
#pragma unroll
        for (int r = 0; r < 4; ++r) {
            int i = i0 + ty * 4 + r;
            hp_part[(size_t)part * n + i] = hpv[r];
            hn_part[(size_t)part * n + i] = hnv[r];
        }
    }
}

__global__ __launch_bounds__(256)
void finalize_k(const float* __restrict__ hp_part, const float* __restrict__ hn_part,
                float* __restrict__ out, int n) {
    float total = 0.f, cnt = 0.f;
    for (int i = threadIdx.x; i < n; i += 256) {
        float hp = -INFINITY, hn = INFINITY;
#pragma unroll
        for (int k = 0; k < NPART; ++k) {
            hp = fmaxf(hp, hp_part[(size_t)k * n + i]);
            hn = fminf(hn, hn_part[(size_t)k * n + i]);
        }
        // hp in {-inf} U [0,inf), hn in [0,inf) U {+inf}: no NaN possible and
        // tl>0 <=> (has_pos && has_neg && relu(hp-hn+margin)>0)
        float tl = hp - hn + 1.0f;
        if (tl > 0.f) { total += tl; cnt += 1.f; }
    }
#pragma unroll
    for (int off = 1; off < 64; off <<= 1) {
        total += __shfl_xor(total, off, 64);
        cnt   += __shfl_xor(cnt,   off, 64);
    }
    __shared__ float sT[4], sC[4];
    int wave = threadIdx.x >> 6;
    if ((threadIdx.x & 63) == 0) { sT[wave] = total; sC[wave] = cnt; }
    __syncthreads();
    if (threadIdx.x == 0) {
        float T  = sT[0] + sT[1] + sT[2] + sT[3];
        float Cn = sC[0] + sC[1] + sC[2] + sC[3];
        out[0] = (Cn > 0.f) ? (T / Cn) : 0.f;
    }
}

extern "C" void kernel_launch(void* const* d_in, const int* in_sizes, int n_in,
                              void* d_out, int out_size, void* d_ws, size_t ws_size,
                              hipStream_t stream) {
    const float* emb = (const float*)d_in[0];
    const int*   lab = (const int*)d_in[1];
    int n = in_sizes[1];               // 8192

    float* sq = (float*)d_ws;          // [n]
    float* hp = sq + n;                // [NPART][n]
    float* hn = hp + (size_t)NPART * n;// [NPART][n]

    sqnorm_k<<<dim3((n + 255) / 256), dim3(256), 0, stream>>>(emb, sq, n);
    hardest_k<<<dim3((n / BM) * NPART), dim3(256), 0, stream>>>(emb, lab, sq, hp, hn, n);
    finalize_k<<<dim3(1), dim3(256), 0, stream>>>(hp, hn, (float*)d_out, n);
}

// Round 2
// 89.322 us; speedup vs baseline: 5.1901x; 5.1901x over previous
//
#include <hip/hip_runtime.h>
#include <hip/hip_bf16.h>
#include <math.h>

#define NN    8192
#define DD    128
#define BM    128      // rows per block (4 waves x 32)
#define BN    64       // cols per j-tile
#define NPART 16       // j-range partitions; grid = 64*16 = 1024 blocks

typedef __attribute__((ext_vector_type(8))) short bf16x8;
typedef __attribute__((ext_vector_type(4))) float f32x4;

static __device__ __forceinline__ ushort f2bf(float x) {
    __hip_bfloat16 h = __float2bfloat16(x);
    return *reinterpret_cast<ushort*>(&h);
}
static __device__ __forceinline__ float bf2f(ushort u) {
    __hip_bfloat16 h = *reinterpret_cast<__hip_bfloat16*>(&u);
    return __bfloat162float(h);
}

__global__ __launch_bounds__(256)
void sqnorm_k(const float* __restrict__ emb, float* __restrict__ sq, int n) {
    int i = blockIdx.x * blockDim.x + threadIdx.x;
    if (i >= n) return;
    const float4* r = reinterpret_cast<const float4*>(emb) + (size_t)i * (DD / 4);
    float s = 0.f;
#pragma unroll
    for (int k = 0; k < DD / 4; ++k) {
        float4 v = r[k];
        s = fmaf(v.x, v.x, s); s = fmaf(v.y, v.y, s);
        s = fmaf(v.z, v.z, s); s = fmaf(v.w, v.w, s);
    }
    sq[i] = s;
}

// elementwise fp32 -> bf16 hi/lo split
__global__ __launch_bounds__(256)
void split_k(const float* __restrict__ emb, ushort* __restrict__ hi,
             ushort* __restrict__ lo, int total4) {
    int i = blockIdx.x * 256 + threadIdx.x;   // float4 index
    if (i >= total4) return;
    float4 v = reinterpret_cast<const float4*>(emb)[i];
    ushort4 h, l;
    float f;
    h.x = f2bf(v.x); f = bf2f(h.x); l.x = f2bf(v.x - f);
    h.y = f2bf(v.y); f = bf2f(h.y); l.y = f2bf(v.y - f);
    h.z = f2bf(v.z); f = bf2f(h.z); l.z = f2bf(v.z - f);
    h.w = f2bf(v.w); f = bf2f(h.w); l.w = f2bf(v.w - f);
    reinterpret_cast<ushort4*>(hi)[i] = h;
    reinterpret_cast<ushort4*>(lo)[i] = l;
}

__global__ __launch_bounds__(256, 2)
void hardest_k(const ushort* __restrict__ embH, const ushort* __restrict__ embL,
               const int* __restrict__ lab, const float* __restrict__ sq,
               float* __restrict__ hp2_part, float* __restrict__ hn2_part) {
    // LDS: B tile (64 rows x 128 bf16), hi+lo, 16B-chunk XOR-swizzled per row
    __shared__ __align__(16) ushort Bh[BN][DD];
    __shared__ __align__(16) ushort Bl[BN][DD];
    __shared__ float sqB[BN];
    __shared__ int   lbB[BN];

    const int tid  = threadIdx.x;
    const int w    = tid >> 6;        // wave 0..3
    const int lane = tid & 63;
    const int lrow = lane & 15;       // fragment row/col index
    const int lk   = lane >> 4;       // k-group 0..3

    const int ib   = (int)blockIdx.x >> 4;    // 0..63
    const int part = (int)blockIdx.x & 15;    // 0..15
    const int i0   = ib * BM;
    const int jbeg = part * (NN / NPART);     // 512-wide j range -> 8 tiles

    // persistent A fragments: 2 strips x 4 k-chunks, hi+lo (64 VGPR)
    bf16x8 ah[2][4], al[2][4];
#pragma unroll
    for (int s = 0; s < 2; ++s) {
        int arow = i0 + w * 32 + s * 16 + lrow;
#pragma unroll
        for (int q = 0; q < 4; ++q) {
            ah[s][q] = *reinterpret_cast<const bf16x8*>(&embH[(size_t)arow * DD + q * 32 + lk * 8]);
            al[s][q] = *reinterpret_cast<const bf16x8*>(&embL[(size_t)arow * DD + q * 32 + lk * 8]);
        }
    }
    // epilogue row metadata: output row = lk*4 + t within each 16-strip
    float eSq[2][4];
    int   eLab[2][4];
#pragma unroll
    for (int s = 0; s < 2; ++s)
#pragma unroll
        for (int t = 0; t < 4; ++t) {
            int i = i0 + w * 32 + s * 16 + lk * 4 + t;
            eSq[s][t]  = sq[i];
            eLab[s][t] = lab[i];
        }

    float hpv[2][4], hnv[2][4];
#pragma unroll
    for (int s = 0; s < 2; ++s)
#pragma unroll
        for (int t = 0; t < 4; ++t) { hpv[s][t] = -INFINITY; hnv[s][t] = INFINITY; }

#pragma unroll 1
    for (int jt = 0; jt < (NN / NPART) / BN; ++jt) {
        const int j0 = jbeg + jt * BN;
        __syncthreads();   // previous tile's compute done
        // stage B tile via global_load_lds (16B), source pre-swizzled:
        // LDS linear dest; logical chunk c placed at phys chunk pc = c ^ (row&7)
#pragma unroll
        for (int m = 0; m < 8; ++m) {
            int idx  = w * 8 + m;          // 0..31
            int inst = idx & 15;           // 1KB instruction index within half
            int row  = inst * 4 + (lane >> 4);
            int c    = (lane & 15) ^ (row & 7);
            const ushort* g = ((idx >> 4) ? embL : embH) + (((size_t)(j0 + row)) << 7) + c * 8;
            ushort* l = ((idx >> 4) ? &Bl[0][0] : &Bh[0][0]) + inst * 512;
            __builtin_amdgcn_global_load_lds(
                (const __attribute__((address_space(1))) uint32_t*)g,
                (__attribute__((address_space(3))) uint32_t*)l, 16, 0, 0);
        }
        if (tid < BN) {
            sqB[tid] = sq[j0 + tid];
            lbB[tid] = lab[j0 + tid];
        }
        __syncthreads();   // staged data visible

        f32x4 acc[2][4];
#pragma unroll
        for (int s = 0; s < 2; ++s)
#pragma unroll
            for (int c = 0; c < 4; ++c) acc[s][c] = (f32x4){0.f, 0.f, 0.f, 0.f};

#pragma unroll
        for (int c = 0; c < 4; ++c) {
            const int col = c * 16 + lrow;
            const int xr  = col & 7;
#pragma unroll
            for (int q = 0; q < 4; ++q) {
                int pc = (q * 4 + lk) ^ xr;
                bf16x8 bh = *reinterpret_cast<const bf16x8*>(&Bh[col][pc * 8]);
                bf16x8 bl = *reinterpret_cast<const bf16x8*>(&Bl[col][pc * 8]);
#pragma unroll
                for (int s = 0; s < 2; ++s) {
                    acc[s][c] = __builtin_amdgcn_mfma_f32_16x16x32_bf16(ah[s][q], bh, acc[s][c], 0, 0, 0);
                    acc[s][c] = __builtin_amdgcn_mfma_f32_16x16x32_bf16(ah[s][q], bl, acc[s][c], 0, 0, 0);
                    acc[s][c] = __builtin_amdgcn_mfma_f32_16x16x32_bf16(al[s][q], bh, acc[s][c], 0, 0, 0);
                }
            }
        }

        // epilogue on squared distances (sqrt deferred to finalize; monotone)
#pragma unroll
        for (int c = 0; c < 4; ++c) {
            const int j   = j0 + c * 16 + lrow;
            const float sqj = sqB[c * 16 + lrow];
            const int   lbj = lbB[c * 16 + lrow];
#pragma unroll
            for (int s = 0; s < 2; ++s)
#pragma unroll
                for (int t = 0; t < 4; ++t) {
                    int i = i0 + w * 32 + s * 16 + lk * 4 + t;
                    float d2 = fmaf(-2.f, acc[s][c][t], eSq[s][t] + sqj);
                    bool same = (eLab[s][t] == lbj);
                    float dpos = (same && (i != j)) ? d2 : -INFINITY;
                    float dneg = same ? INFINITY : d2;
                    hpv[s][t] = fmaxf(hpv[s][t], dpos);
                    hnv[s][t] = fminf(hnv[s][t], dneg);
                }
        }
    }

    // reduce across the 16 lanes (lrow) sharing each output row
#pragma unroll
    for (int off = 1; off < 16; off <<= 1) {
#pragma unroll
        for (int s = 0; s < 2; ++s)
#pragma unroll
            for (int t = 0; t < 4; ++t) {
                hpv[s][t] = fmaxf(hpv[s][t], __shfl_xor(hpv[s][t], off, 64));
                hnv[s][t] = fminf(hnv[s][t], __shfl_xor(hnv[s][t], off, 64));
            }
    }
    if (lrow == 0) {
#pragma unroll
        for (int s = 0; s < 2; ++s)
#pragma unroll
            for (int t = 0; t < 4; ++t) {
                int i = i0 + w * 32 + s * 16 + lk * 4 + t;
                hp2_part[(size_t)part * NN + i] = hpv[s][t];
                hn2_part[(size_t)part * NN + i] = hnv[s][t];
            }
    }
}

__global__ __launch_bounds__(256)
void finalize_k(const float* __restrict__ hp2_part, const float* __restrict__ hn2_part,
                float* __restrict__ out) {
    float total = 0.f, cnt = 0.f;
    for (int i = threadIdx.x; i < NN; i += 256) {
        float hp2 = -INFINITY, hn2 = INFINITY;
#pragma unroll
        for (int k = 0; k < NPART; ++k) {
            hp2 = fmaxf(hp2, hp2_part[(size_t)k * NN + i]);
            hn2 = fminf(hn2, hn2_part[(size_t)k * NN + i]);
        }
        float hp = (hp2 > -INFINITY) ? sqrtf(fmaxf(hp2, 0.f)) : -INFINITY;
        float hn = (hn2 <  INFINITY) ? sqrtf(fmaxf(hn2, 0.f)) :  INFINITY;
        float tl = hp - hn + 1.0f;      // -inf propagates; tl>0 <=> valid & positive
        if (tl > 0.f) { total += tl; cnt += 1.f; }
    }
#pragma unroll
    for (int off = 1; off < 64; off <<= 1) {
        total += __shfl_xor(total, off, 64);
        cnt   += __shfl_xor(cnt,   off, 64);
    }
    __shared__ float sT[4], sC[4];
    int wave = threadIdx.x >> 6;
    if ((threadIdx.x & 63) == 0) { sT[wave] = total; sC[wave] = cnt; }
    __syncthreads();
    if (threadIdx.x == 0) {
        float T  = sT[0] + sT[1] + sT[2] + sT[3];
        float Cn = sC[0] + sC[1] + sC[2] + sC[3];
        out[0] = (Cn > 0.f) ? (T / Cn) : 0.f;
    }
}

extern "C" void kernel_launch(void* const* d_in, const int* in_sizes, int n_in,
                              void* d_out, int out_size, void* d_ws, size_t ws_size,
                              hipStream_t stream) {
    const float* emb = (const float*)d_in[0];
    const int*   lab = (const int*)d_in[1];

    char* ws = (char*)d_ws;
    float*  sq   = (float*)ws;                         // 32 KB
    float*  hp2  = (float*)(ws + 32768);               // 512 KB
    float*  hn2  = (float*)(ws + 32768 + 524288);      // 512 KB
    ushort* embH = (ushort*)(ws + 32768 + 2 * 524288);          // 2 MB
    ushort* embL = (ushort*)(ws + 32768 + 2 * 524288 + 2097152);// 2 MB

    sqnorm_k<<<dim3(NN / 256), dim3(256), 0, stream>>>(emb, sq, NN);
    split_k<<<dim3((NN * DD / 4) / 256), dim3(256), 0, stream>>>(emb, embH, embL, NN * DD / 4);
    hardest_k<<<dim3((NN / BM) * NPART), dim3(256), 0, stream>>>(embH, embL, lab, sq, hp2, hn2);
    finalize_k<<<dim3(1), dim3(256), 0, stream>>>(hp2, hn2, (float*)d_out);
}

// Round 3
// 59.673 us; speedup vs baseline: 7.7690x; 1.4969x over previous
//
#include <hip/hip_runtime.h>
#include <math.h>

#define NN 8192
#define DD 128
#define BM 256        // rows per block (4 waves x 64)
#define BN 64         // cols per j-tile
#define NPART 16      // grid = 32*16 = 512 blocks
#define JRANGE (NN / NPART)   // 512
#define NTILES (JRANGE / BN)  // 8

typedef __attribute__((ext_vector_type(4))) int i32x4;

// ws byte offsets
#define WS_SCALE   0
#define WS_PARTIAL 256                         // 256 floats
#define WS_SQ      4096                        // 8192 floats
#define WS_PT      36864                       // 32 floats
#define WS_PC      37120                       // 32 floats
#define WS_HPG     40960                       // 16*8192 floats
#define WS_HNG     (40960 + 524288)
#define WS_AH      (40960 + 2 * 524288)        // 262144 ints (1MB)
#define WS_AL      (40960 + 2 * 524288 + 1048576)

// one pass over emb: per-row sqnorm + per-block absmax partial
__global__ __launch_bounds__(256)
void prep_k(const float* __restrict__ emb, float* __restrict__ sq,
            float* __restrict__ partial) {
    int g = blockIdx.x * 256 + threadIdx.x;
    int row = g >> 3, part = g & 7;
    const float4* p = reinterpret_cast<const float4*>(emb) + row * 32 + part * 4;
    float s = 0.f, m = 0.f;
#pragma unroll
    for (int k = 0; k < 4; ++k) {
        float4 v = p[k];
        s = fmaf(v.x, v.x, s); s = fmaf(v.y, v.y, s);
        s = fmaf(v.z, v.z, s); s = fmaf(v.w, v.w, s);
        m = fmaxf(m, fmaxf(fmaxf(fabsf(v.x), fabsf(v.y)),
                           fmaxf(fabsf(v.z), fabsf(v.w))));
    }
#pragma unroll
    for (int off = 1; off < 8; off <<= 1) s += __shfl_xor(s, off, 64);
    if (part == 0) sq[row] = s;
#pragma unroll
    for (int off = 1; off < 64; off <<= 1) m = fmaxf(m, __shfl_xor(m, off, 64));
    __shared__ float sm[4];
    if ((threadIdx.x & 63) == 0) sm[threadIdx.x >> 6] = m;
    __syncthreads();
    if (threadIdx.x == 0)
        partial[blockIdx.x] = fmaxf(fmaxf(sm[0], sm[1]), fmaxf(sm[2], sm[3]));
}

// fp32 -> i8 hi/lo quantization (x ~= sA*a + (sA/256)*b), packed 4/int
__global__ __launch_bounds__(256)
void quantize_k(const float* __restrict__ emb, const float* __restrict__ partial,
                int* __restrict__ aH, int* __restrict__ aL,
                float* __restrict__ scale) {
    __shared__ float sm[4];
    float m = partial[threadIdx.x];
#pragma unroll
    for (int off = 1; off < 64; off <<= 1) m = fmaxf(m, __shfl_xor(m, off, 64));
    if ((threadIdx.x & 63) == 0) sm[threadIdx.x >> 6] = m;
    __syncthreads();
    float amax = fmaxf(fmaxf(sm[0], sm[1]), fmaxf(sm[2], sm[3]));
    float sA  = amax * (1.0f / 127.0f);
    float inv = 1.0f / sA;
    int i = blockIdx.x * 256 + threadIdx.x;   // float4 index, grid covers exactly
    float4 v = reinterpret_cast<const float4*>(emb)[i];
    float xs0 = v.x, xs1 = v.y, xs2 = v.z, xs3 = v.w;
    int h = 0, l = 0;
#define QSTEP(X, K) { \
        float a = rintf((X) * inv); \
        a = fminf(fmaxf(a, -127.f), 127.f); \
        float r = fmaf(-a, sA, (X)); \
        float b = rintf(r * inv * 256.0f); \
        b = fminf(fmaxf(b, -127.f), 127.f); \
        h |= ((int)a & 255) << (8 * (K)); \
        l |= ((int)b & 255) << (8 * (K)); }
    QSTEP(xs0, 0) QSTEP(xs1, 1) QSTEP(xs2, 2) QSTEP(xs3, 3)
#undef QSTEP
    aH[i] = h; aL[i] = l;
    if (blockIdx.x == 0 && threadIdx.x == 0) scale[0] = sA;
}

__global__ __launch_bounds__(256, 2)
void hardest_k(const int* __restrict__ aH, const int* __restrict__ aL,
               const int* __restrict__ lab, const float* __restrict__ sq,
               const float* __restrict__ scale,
               float* __restrict__ hpg_o, float* __restrict__ hng_o) {
    const int tid  = threadIdx.x;
    const int w    = tid >> 6;
    const int lane = tid & 63;
    const int lrow = lane & 15;
    const int lk   = lane >> 4;
    const int ib   = (int)blockIdx.x >> 4;
    const int part = (int)blockIdx.x & 15;
    const int i0   = ib * BM;
    const int jbeg = part * JRANGE;
    const float sA  = scale[0];
    const float cst = -(sA * sA) * (1.0f / 128.0f);   // g = sqj - 2*dot = fma(cst, e, sqj)

    // persistent A fragments: 4 strips of 16 rows, K=128 in 2 chunks, hi+lo
    i32x4 ah[4][2], al[4][2];
#pragma unroll
    for (int s = 0; s < 4; ++s) {
        int row = i0 + w * 64 + s * 16 + lrow;
#pragma unroll
        for (int q = 0; q < 2; ++q) {
            ah[s][q] = *reinterpret_cast<const i32x4*>(&aH[row * 32 + q * 16 + lk * 4]);
            al[s][q] = *reinterpret_cast<const i32x4*>(&aL[row * 32 + q * 16 + lk * 4]);
        }
    }
    int   li[4][4];
    float hpg[4][4], hng[4][4];
#pragma unroll
    for (int s = 0; s < 4; ++s)
#pragma unroll
        for (int t = 0; t < 4; ++t) {
            li[s][t]  = lab[i0 + w * 64 + s * 16 + lk * 4 + t];
            hpg[s][t] = -INFINITY;
            hng[s][t] =  INFINITY;
        }

#pragma unroll 1
    for (int jt = 0; jt < NTILES; ++jt) {
        const int j0 = jbeg + jt * BN;
#pragma unroll
        for (int c = 0; c < 4; ++c) {
            const int jrow = j0 + c * 16 + lrow;
            i32x4 bh0 = *reinterpret_cast<const i32x4*>(&aH[jrow * 32 + 0  + lk * 4]);
            i32x4 bh1 = *reinterpret_cast<const i32x4*>(&aH[jrow * 32 + 16 + lk * 4]);
            i32x4 bl0 = *reinterpret_cast<const i32x4*>(&aL[jrow * 32 + 0  + lk * 4]);
            i32x4 bl1 = *reinterpret_cast<const i32x4*>(&aL[jrow * 32 + 16 + lk * 4]);
            i32x4 accA[4], accB[4];
            i32x4 zero = {0, 0, 0, 0};
#pragma unroll
            for (int s = 0; s < 4; ++s) { accA[s] = zero; accB[s] = zero; }
#pragma unroll
            for (int s = 0; s < 4; ++s) {
                accA[s] = __builtin_amdgcn_mfma_i32_16x16x64_i8(ah[s][0], bh0, accA[s], 0, 0, 0);
                accA[s] = __builtin_amdgcn_mfma_i32_16x16x64_i8(ah[s][1], bh1, accA[s], 0, 0, 0);
                accB[s] = __builtin_amdgcn_mfma_i32_16x16x64_i8(ah[s][0], bl0, accB[s], 0, 0, 0);
                accB[s] = __builtin_amdgcn_mfma_i32_16x16x64_i8(ah[s][1], bl1, accB[s], 0, 0, 0);
                accB[s] = __builtin_amdgcn_mfma_i32_16x16x64_i8(al[s][0], bh0, accB[s], 0, 0, 0);
                accB[s] = __builtin_amdgcn_mfma_i32_16x16x64_i8(al[s][1], bh1, accB[s], 0, 0, 0);
            }
            const float sqj = sq[jrow];   // this lane's column j = jrow
            const int   lj  = lab[jrow];
#pragma unroll
            for (int s = 0; s < 4; ++s)
#pragma unroll
                for (int t = 0; t < 4; ++t) {
                    int   e  = (accA[s][t] << 8) + accB[s][t];   // exact, < 2^30
                    float gg = fmaf(cst, (float)e, sqj);         // g = sqj - 2*dot
                    bool same = (li[s][t] == lj);
                    hpg[s][t] = fmaxf(hpg[s][t], same ? gg : -INFINITY);
                    hng[s][t] = fminf(hng[s][t], same ? INFINITY : gg);
                }
        }
    }
    // reduce over the 16 column-lanes sharing each output row
#pragma unroll
    for (int off = 1; off < 16; off <<= 1)
#pragma unroll
        for (int s = 0; s < 4; ++s)
#pragma unroll
            for (int t = 0; t < 4; ++t) {
                hpg[s][t] = fmaxf(hpg[s][t], __shfl_xor(hpg[s][t], off, 64));
                hng[s][t] = fminf(hng[s][t], __shfl_xor(hng[s][t], off, 64));
            }
    if (lrow == 0) {
#pragma unroll
        for (int s = 0; s < 4; ++s)
#pragma unroll
            for (int t = 0; t < 4; ++t) {
                int i = i0 + w * 64 + s * 16 + lk * 4 + t;
                hpg_o[part * NN + i] = hpg[s][t];
                hng_o[part * NN + i] = hng[s][t];
            }
    }
}

__global__ __launch_bounds__(256)
void combine_k(const float* __restrict__ hpg, const float* __restrict__ hng,
               const float* __restrict__ sq, float* __restrict__ pT,
               float* __restrict__ pC) {
    int i = blockIdx.x * 256 + threadIdx.x;
    float hp = -INFINITY, hn = INFINITY;
#pragma unroll
    for (int p = 0; p < NPART; ++p) {
        hp = fmaxf(hp, hpg[p * NN + i]);
        hn = fminf(hn, hng[p * NN + i]);
    }
    float s = sq[i];
    float hp2 = s + hp, hn2 = s + hn;                 // d^2 = sq_i + g
    float hpd = (hp2 == -INFINITY) ? -INFINITY : sqrtf(fmaxf(hp2, 0.f));
    float hnd = (hn2 ==  INFINITY) ?  INFINITY : sqrtf(fmaxf(hn2, 0.f));
    float tl = hpd - hnd + 1.0f;                      // -inf propagates, no NaN
    float tsum = (tl > 0.f) ? tl : 0.f;
    float tcnt = (tl > 0.f) ? 1.f : 0.f;
#pragma unroll
    for (int off = 1; off < 64; off <<= 1) {
        tsum += __shfl_xor(tsum, off, 64);
        tcnt += __shfl_xor(tcnt, off, 64);
    }
    __shared__ float sT[4], sC[4];
    if ((threadIdx.x & 63) == 0) { sT[threadIdx.x >> 6] = tsum; sC[threadIdx.x >> 6] = tcnt; }
    __syncthreads();
    if (threadIdx.x == 0) {
        pT[blockIdx.x] = sT[0] + sT[1] + sT[2] + sT[3];
        pC[blockIdx.x] = sC[0] + sC[1] + sC[2] + sC[3];
    }
}

__global__ __launch_bounds__(64)
void final_k(const float* __restrict__ pT, const float* __restrict__ pC,
             float* __restrict__ out) {
    float t = (threadIdx.x < 32) ? pT[threadIdx.x] : 0.f;
    float c = (threadIdx.x < 32) ? pC[threadIdx.x] : 0.f;
#pragma unroll
    for (int off = 1; off < 32; off <<= 1) {
        t += __shfl_xor(t, off, 64);
        c += __shfl_xor(c, off, 64);
    }
    if (threadIdx.x == 0) out[0] = (c > 0.f) ? t / c : 0.f;
}

extern "C" void kernel_launch(void* const* d_in, const int* in_sizes, int n_in,
                              void* d_out, int out_size, void* d_ws, size_t ws_size,
                              hipStream_t stream) {
    const float* emb = (const float*)d_in[0];
    const int*   lab = (const int*)d_in[1];
    char* ws = (char*)d_ws;
    float* scale   = (float*)(ws + WS_SCALE);
    float* partial = (float*)(ws + WS_PARTIAL);
    float* sq      = (float*)(ws + WS_SQ);
    float* pT      = (float*)(ws + WS_PT);
    float* pC      = (float*)(ws + WS_PC);
    float* hpg     = (float*)(ws + WS_HPG);
    float* hng     = (float*)(ws + WS_HNG);
    int*   aH      = (int*)(ws + WS_AH);
    int*   aL      = (int*)(ws + WS_AL);

    prep_k<<<dim3(256), dim3(256), 0, stream>>>(emb, sq, partial);
    quantize_k<<<dim3(1024), dim3(256), 0, stream>>>(emb, partial, aH, aL, scale);
    hardest_k<<<dim3((NN / BM) * NPART), dim3(256), 0, stream>>>(aH, aL, lab, sq, scale, hpg, hng);
    combine_k<<<dim3(NN / 256), dim3(256), 0, stream>>>(hpg, hng, sq, pT, pC);
    final_k<<<dim3(1), dim3(64), 0, stream>>>(pT, pC, (float*)d_out);
}